// Round 5
// baseline (453.839 us; speedup 1.0000x reference)
//
#include <hip/hip_runtime.h>

#define LL 32
#define HH 64

// Broadcast lane `lane`'s value of v to all lanes via v_readlane (result is
// wave-uniform, lands in an SGPR; consumed directly by v_fmac as the scalar op).
__device__ __forceinline__ float bcast_lane(float v, int lane) {
  return __builtin_bit_cast(float, __builtin_amdgcn_readlane(__builtin_bit_cast(int, v), lane));
}

// One DPP-shifted add step (bound_ctrl: out-of-range lanes contribute 0).
template <int CTRL>
__device__ __forceinline__ float dpp_add_step(float x) {
  int y = __builtin_amdgcn_update_dpp(0, __builtin_bit_cast(int, x), CTRL, 0xf, 0xf, true);
  return x + __builtin_bit_cast(float, y);
}

// Full 64-lane sum, result broadcast as a wave-uniform value (via readlane 63).
__device__ __forceinline__ float wave_sum64(float x) {
  x = dpp_add_step<0x111>(x);  // row_shr:1
  x = dpp_add_step<0x112>(x);  // row_shr:2
  x = dpp_add_step<0x114>(x);  // row_shr:4
  x = dpp_add_step<0x118>(x);  // row_shr:8
  x = dpp_add_step<0x142>(x);  // row_bcast15
  x = dpp_add_step<0x143>(x);  // row_bcast31
  return __builtin_bit_cast(float, __builtin_amdgcn_readlane(__builtin_bit_cast(int, x), 63));
}

// Wc column j held as 64 *named* scalars — no array, no alloca, so SROA can't
// fail and the allocator has no scratch fallback. (R2-R4: `float wcol[64]`
// ended up in scratch — VGPR_Count stuck at 44, ~64 reloads/step, ~950 cyc/step.)
#define DECL_W(n) float w_##n = Wc[n * HH + lane];
#define MV4(i0, i1, i2, i3)                  \
  a0 = fmaf(bcast_lane(hv, i0), w_##i0, a0); \
  a1 = fmaf(bcast_lane(hv, i1), w_##i1, a1); \
  a2 = fmaf(bcast_lane(hv, i2), w_##i2, a2); \
  a3 = fmaf(bcast_lane(hv, i3), w_##i3, a3);

// One wave (64 lanes) per sample; lane j owns hidden unit j. 1024 blocks of one
// wave each = 1 wave/SIMD on 1024 SIMDs — occupancy is structural, so give the
// allocator the whole register file (waves/EU = 1 -> 512 VGPR budget).
__global__ __launch_bounds__(64, 1) void rnn2d_kernel(
    const int* __restrict__ x, const float* __restrict__ Win,
    const float* __restrict__ Wc, const float* __restrict__ bc,
    const float* __restrict__ Wout, const float* __restrict__ bout,
    float* __restrict__ out) {
  const int lane = threadIdx.x;
  const int b = blockIdx.x;
  __shared__ float vrow[LL * HH];  // [column][hidden] — lane j only touches [.][j]

  DECL_W(0)  DECL_W(1)  DECL_W(2)  DECL_W(3)  DECL_W(4)  DECL_W(5)  DECL_W(6)  DECL_W(7)
  DECL_W(8)  DECL_W(9)  DECL_W(10) DECL_W(11) DECL_W(12) DECL_W(13) DECL_W(14) DECL_W(15)
  DECL_W(16) DECL_W(17) DECL_W(18) DECL_W(19) DECL_W(20) DECL_W(21) DECL_W(22) DECL_W(23)
  DECL_W(24) DECL_W(25) DECL_W(26) DECL_W(27) DECL_W(28) DECL_W(29) DECL_W(30) DECL_W(31)
  DECL_W(32) DECL_W(33) DECL_W(34) DECL_W(35) DECL_W(36) DECL_W(37) DECL_W(38) DECL_W(39)
  DECL_W(40) DECL_W(41) DECL_W(42) DECL_W(43) DECL_W(44) DECL_W(45) DECL_W(46) DECL_W(47)
  DECL_W(48) DECL_W(49) DECL_W(50) DECL_W(51) DECL_W(52) DECL_W(53) DECL_W(54) DECL_W(55)
  DECL_W(56) DECL_W(57) DECL_W(58) DECL_W(59) DECL_W(60) DECL_W(61) DECL_W(62) DECL_W(63)

  const float win0 = Win[lane];                  // Win[0][j]
  const float win1 = Win[HH + lane];             // Win[1][j]
  const float bcj = bc[lane];
  const float dwout = Wout[lane * 2 + 1] - Wout[lane * 2 + 0];  // (Wout[j][1]-Wout[j][0])
  const float dbout = bout[1] - bout[0];         // wave-uniform scalar

  // Row 0 sees zero vertical hidden carry.
#pragma unroll
  for (int c0 = 0; c0 < LL; ++c0) vrow[c0 * HH + lane] = 0.f;

  const int* xb = x + b * (LL * LL);
  unsigned prevmask = 0u;                // previous row's spins (bit c = spin at column c)
  int spv = (lane < LL) ? xb[lane] : 0;  // prefetched row-0 spins
  float total = 0.f;

#pragma unroll 1
  for (int r = 0; r < LL; ++r) {
    const unsigned curmask =
        (unsigned)(__ballot(lane < LL && spv) & 0xffffffffull);
    if (r < LL - 1) spv = (lane < LL) ? xb[(r + 1) * LL + lane] : 0;  // prefetch next row

    const int odd = r & 1;
    const int d = odd ? -1 : 1;       // boustrophedon direction
    int c = odd ? (LL - 1) : 0;       // spatial column of scan step 0
    float hcur = 0.f;                 // horizontal hidden carry (zero at row start)
    float vj = vrow[c * HH + lane];   // vertical carry for step 0

#pragma unroll 1
    for (int k = 0; k < LL; ++k) {
      // Prefetch next step's vertical carry (column not yet overwritten this row).
      const int cn = (c + d) & (LL - 1);
      const float vj_next = vrow[cn * HH + lane];

      const float hv = hcur + vj;  // (h + cV)[j], broadcast across lanes below

      // newH[j] = sum_i hv[i] * Wc[i][j]: 64 readlane-broadcasts + 64 FMAs,
      // 4 independent accumulator chains.
      float a0 = 0.f, a1 = 0.f, a2 = 0.f, a3 = 0.f;
      MV4(0, 1, 2, 3)     MV4(4, 5, 6, 7)     MV4(8, 9, 10, 11)   MV4(12, 13, 14, 15)
      MV4(16, 17, 18, 19) MV4(20, 21, 22, 23) MV4(24, 25, 26, 27) MV4(28, 29, 30, 31)
      MV4(32, 33, 34, 35) MV4(36, 37, 38, 39) MV4(40, 41, 42, 43) MV4(44, 45, 46, 47)
      MV4(48, 49, 50, 51) MV4(52, 53, 54, 55) MV4(56, 57, 58, 59) MV4(60, 61, 62, 63)

      // newR @ Win: one-hot row selects (spins are wave-uniform bits of the masks).
      float winc = 0.f;
      if (k > 0) {  // horizontal neighbor (previously visited site in this row)
        const unsigned sh = (curmask >> ((c - d) & 31)) & 1u;
        winc += sh ? win1 : win0;
      }
      if (r > 0) {  // vertical neighbor (same column, previous row)
        const unsigned sv = (prevmask >> c) & 1u;
        winc += sv ? win1 : win0;
      }

      const float pre = ((a0 + a1) + (a2 + a3)) + bcj + winc;
      // elu
      const float hnew = pre > 0.f ? pre : (__expf(pre) - 1.f);

      vrow[c * HH + lane] = hnew;  // vertical carry for next row
      hcur = hnew;

      // 2-class log-softmax via single reduction:
      //   dz = z1 - z0;  t = z_other - z_chosen = spin ? -dz : dz
      //   logp = -softplus(t) = -(max(t,0) + log1p(exp(-|t|)))
      // identical to the reference's max-subtracted form; NaN in dz propagates
      // through the log1p term -> caught by the -35 replacement.
      const float dz = wave_sum64(hnew * dwout) + dbout;
      const unsigned spin = (curmask >> c) & 1u;
      const float t = spin ? -dz : dz;
      const float lp = -(fmaxf(t, 0.f) + __logf(1.f + __expf(-fabsf(t))));
      total += (lp == lp) ? lp : -35.0f;  // nan_to_num(nan=-35)

      vj = vj_next;
      c = cn;
    }
    prevmask = curmask;
  }

  if (lane == 0) out[b] = 0.5f * total;  // LOGP_FACTOR * sum
}

extern "C" void kernel_launch(void* const* d_in, const int* in_sizes, int n_in,
                              void* d_out, int out_size, void* d_ws, size_t ws_size,
                              hipStream_t stream) {
  const int* x = (const int*)d_in[0];
  const float* Win = (const float*)d_in[1];
  const float* Wc = (const float*)d_in[2];
  const float* bc = (const float*)d_in[3];
  const float* Wout = (const float*)d_in[4];
  const float* bout = (const float*)d_in[5];
  float* out = (float*)d_out;
  // One 64-thread block (one wave) per batch sample.
  rnn2d_kernel<<<dim3(out_size), dim3(64), 0, stream>>>(x, Win, Wc, bc, Wout, bout, out);
}